// Round 2
// baseline (451.022 us; speedup 1.0000x reference)
//
#include <hip/hip_runtime.h>

// ws layout (floats): 60 * 8 fused gate matrices U = RZ*RY*RX (layer-major)
#define WS_U 0

// ---------------- prep: build fused gate matrices from q_params (f32) -------
__global__ void k_prep(const float* __restrict__ qp, float* __restrict__ ws)
{
    int t = threadIdx.x;
    if (t >= 60) return;
    int l = t / 10;
    float tx = 0.5f * qp[t*3 + 0];
    float ty = 0.5f * qp[t*3 + 1];
    float tz = 0.5f * qp[t*3 + 2];
    float cx = cosf(tx), sx = sinf(tx);
    float cy = cosf(ty), sy = sinf(ty);
    float cz, sz;
    if (l == 5) { cz = 1.0f; sz = 0.0f; }   // final-layer RZ commutes with Z readout: drop
    else        { cz = cosf(tz); sz = sinf(tz); }
    // Ry*Rx
    float m00r =  cy*cx, m00i =  sy*sx;
    float m01r = -sy*cx, m01i = -cy*sx;
    float m10r =  sy*cx, m10i = -cy*sx;
    float m11r =  cy*cx, m11i = -sy*sx;
    // Rz * (Ry*Rx): row0 *= (cz - i sz), row1 *= (cz + i sz)
    float* U = ws + WS_U + t*8;
    U[0] = m00r*cz + m00i*sz;  U[1] = m00i*cz - m00r*sz;
    U[2] = m01r*cz + m01i*sz;  U[3] = m01i*cz - m01r*sz;
    U[4] = m10r*cz - m10i*sz;  U[5] = m10i*cz + m10r*sz;
    U[6] = m11r*cz - m11i*sz;  U[7] = m11i*cz + m11r*sz;
}

// ---------------- quantum sim: 1 wave = 1 sample, state in 16 complex regs ---
// qubit q<6  -> lane bit q ; qubit q>=6 -> register bit (q-6)

#define CNOT_CHAIN() {                                                        \
    _Pragma("unroll")                                                         \
    for (int c = 0; c < 5; c++) {                                             \
        bool ctrl = (lane >> c) & 1;                                          \
        _Pragma("unroll")                                                     \
        for (int r = 0; r < 16; r++) {                                        \
            float tr = __shfl_xor(ar[r], 2 << c, 64);                         \
            float ti = __shfl_xor(ai[r], 2 << c, 64);                         \
            ar[r] = ctrl ? tr : ar[r];                                        \
            ai[r] = ctrl ? ti : ai[r];                                        \
        }                                                                     \
    }                                                                         \
    { bool ctrl = (lane >> 5) & 1;  /* CNOT(5,6): swap r<->r^1 if ctrl */     \
      _Pragma("unroll")                                                       \
      for (int r = 0; r < 16; r += 2) {                                       \
        float t0 = ar[r], t1 = ai[r];                                         \
        ar[r]   = ctrl ? ar[r+1] : ar[r];                                     \
        ai[r]   = ctrl ? ai[r+1] : ai[r];                                     \
        ar[r+1] = ctrl ? t0 : ar[r+1];                                        \
        ai[r+1] = ctrl ? t1 : ai[r+1];                                        \
      } }                                                                     \
    { float t; /* CNOT(6,7): odd r <-> r^2 */                                 \
      t=ar[1];ar[1]=ar[3];ar[3]=t;     t=ai[1];ai[1]=ai[3];ai[3]=t;           \
      t=ar[5];ar[5]=ar[7];ar[7]=t;     t=ai[5];ai[5]=ai[7];ai[7]=t;           \
      t=ar[9];ar[9]=ar[11];ar[11]=t;   t=ai[9];ai[9]=ai[11];ai[11]=t;         \
      t=ar[13];ar[13]=ar[15];ar[15]=t; t=ai[13];ai[13]=ai[15];ai[15]=t;       \
      /* CNOT(7,8): bit1 set r <-> r^4 */                                     \
      t=ar[2];ar[2]=ar[6];ar[6]=t;     t=ai[2];ai[2]=ai[6];ai[6]=t;           \
      t=ar[3];ar[3]=ar[7];ar[7]=t;     t=ai[3];ai[3]=ai[7];ai[7]=t;           \
      t=ar[10];ar[10]=ar[14];ar[14]=t; t=ai[10];ai[10]=ai[14];ai[14]=t;       \
      t=ar[11];ar[11]=ar[15];ar[15]=t; t=ai[11];ai[11]=ai[15];ai[15]=t;       \
      /* CNOT(8,9): bit2 set r <-> r^8 */                                     \
      t=ar[4];ar[4]=ar[12];ar[12]=t;   t=ai[4];ai[4]=ai[12];ai[12]=t;         \
      t=ar[5];ar[5]=ar[13];ar[13]=t;   t=ai[5];ai[5]=ai[13];ai[13]=t;         \
      t=ar[6];ar[6]=ar[14];ar[14]=t;   t=ai[6];ai[6]=ai[14];ai[14]=t;         \
      t=ar[7];ar[7]=ar[15];ar[15]=t;   t=ai[7];ai[7]=ai[15];ai[15]=t;         \
    } }

__global__ __launch_bounds__(256) void k_qsim(
        const float* __restrict__ x,
        const float* __restrict__ W1, const float* __restrict__ b1,
        const float* __restrict__ W2, const float* __restrict__ b2,
        const float* __restrict__ ws,
        const float* __restrict__ W3, const float* __restrict__ b3,
        const float* __restrict__ W4, const float* __restrict__ b4,
        float* __restrict__ out)
{
    const int lane = threadIdx.x & 63;
    int wid = (blockIdx.x * 256 + threadIdx.x) >> 6;
    const int s = __builtin_amdgcn_readfirstlane(wid);

    // ---- fused front MLP: x(64) -> relu h(32) -> angles(10) -> cos/sin -----
    float cv[10], sv[10];
    {
        const float* xr  = x + s * 64;           // wave-uniform -> s_loads
        const int j = lane & 31;                 // lanes j and j+32 both do row j
        const float* w1r = W1 + j * 64;
        float a = b1[j];
        #pragma unroll
        for (int k = 0; k < 64; k++) a = fmaf(w1r[k], xr[k], a);
        float h = fmaxf(a, 0.0f);
        #pragma unroll
        for (int i = 0; i < 10; i++) {
            float t = W2[i*32 + j] * h;
            #pragma unroll
            for (int m = 16; m >= 1; m >>= 1) t += __shfl_xor(t, m, 64);
            t += b2[i];
            float ang = tanhf(t) * 1.5707963267948966f;   // (tanh*pi)*0.5
            cv[i] = cosf(ang);
            sv[i] = sinf(ang);
        }
    }

    float ar[16], ai[16];

    // ---- init: RY-encoding product state with layer-0 1q gates folded in ---
    {
        const float* U0 = ws + WS_U;
        float Lr, Li;
        {
            float v0r = U0[0]*cv[0] + U0[2]*sv[0], v0i = U0[1]*cv[0] + U0[3]*sv[0];
            float v1r = U0[4]*cv[0] + U0[6]*sv[0], v1i = U0[5]*cv[0] + U0[7]*sv[0];
            bool b = lane & 1;
            Lr = b ? v1r : v0r;  Li = b ? v1i : v0i;
        }
        #pragma unroll
        for (int q = 1; q < 6; q++) {
            const float* U = U0 + q*8;
            float v0r = U[0]*cv[q] + U[2]*sv[q], v0i = U[1]*cv[q] + U[3]*sv[q];
            float v1r = U[4]*cv[q] + U[6]*sv[q], v1i = U[5]*cv[q] + U[7]*sv[q];
            bool b = (lane >> q) & 1;
            float fr = b ? v1r : v0r, fi = b ? v1i : v0i;
            float nr = Lr*fr - Li*fi;
            float ni = Lr*fi + Li*fr;
            Lr = nr; Li = ni;
        }
        float vr[4][2], vi[4][2];
        #pragma unroll
        for (int q = 6; q < 10; q++) {
            const float* U = U0 + q*8;
            vr[q-6][0] = U[0]*cv[q] + U[2]*sv[q];  vi[q-6][0] = U[1]*cv[q] + U[3]*sv[q];
            vr[q-6][1] = U[4]*cv[q] + U[6]*sv[q];  vi[q-6][1] = U[5]*cv[q] + U[7]*sv[q];
        }
        float t67r[4], t67i[4], t89r[4], t89i[4];
        #pragma unroll
        for (int m = 0; m < 4; m++) {
            int b0 = m & 1, b1i = (m >> 1) & 1;
            t67r[m] = vr[0][b0]*vr[1][b1i] - vi[0][b0]*vi[1][b1i];
            t67i[m] = vr[0][b0]*vi[1][b1i] + vi[0][b0]*vr[1][b1i];
            t89r[m] = vr[2][b0]*vr[3][b1i] - vi[2][b0]*vi[3][b1i];
            t89i[m] = vr[2][b0]*vi[3][b1i] + vi[2][b0]*vr[3][b1i];
        }
        #pragma unroll
        for (int r = 0; r < 16; r++) {
            int lo = r & 3, hi = r >> 2;
            float pr  = t67r[lo]*t89r[hi] - t67i[lo]*t89i[hi];
            float pi_ = t67r[lo]*t89i[hi] + t67i[lo]*t89r[hi];
            ar[r] = Lr*pr - Li*pi_;
            ai[r] = Lr*pi_ + Li*pr;
        }
    }

    // ---- layers: chain(l-1) then gates(l), l = 1..5 (last chain folded) ----
    #pragma unroll 1
    for (int l = 1; l < 6; ++l) {
        CNOT_CHAIN();
        const float* Ub = ws + WS_U + l * 80;
        // lane-bit qubits 0..5
        #pragma unroll
        for (int q = 0; q < 6; q++) {
            const float* U = Ub + q*8;
            float u00r=U[0], u00i=U[1], u01r=U[2], u01i=U[3];
            float u10r=U[4], u10i=U[5], u11r=U[6], u11i=U[7];
            bool hi = (lane >> q) & 1;
            float msr = hi ? u11r : u00r, msi = hi ? u11i : u00i;
            float mor = hi ? u10r : u01r, moi = hi ? u10i : u01i;
            #pragma unroll
            for (int r = 0; r < 16; r++) {
                float o_r = __shfl_xor(ar[r], 1 << q, 64);
                float o_i = __shfl_xor(ai[r], 1 << q, 64);
                float nr = msr*ar[r] - msi*ai[r] + mor*o_r - moi*o_i;
                float ni = msr*ai[r] + msi*ar[r] + mor*o_i + moi*o_r;
                ar[r] = nr; ai[r] = ni;
            }
        }
        // register-bit qubits 6..9
        #pragma unroll
        for (int qq = 0; qq < 4; qq++) {
            const float* U = Ub + (6+qq)*8;
            float u00r=U[0], u00i=U[1], u01r=U[2], u01i=U[3];
            float u10r=U[4], u10i=U[5], u11r=U[6], u11i=U[7];
            const int m = 1 << qq;
            #pragma unroll
            for (int r = 0; r < 16; r++) {
                if (!(r & m)) {
                    const int r2 = r | m;
                    float a0r=ar[r], a0i=ai[r], a1r=ar[r2], a1i=ai[r2];
                    ar[r]  = u00r*a0r - u00i*a0i + u01r*a1r - u01i*a1i;
                    ai[r]  = u00r*a0i + u00i*a0r + u01r*a1i + u01i*a1r;
                    ar[r2] = u10r*a0r - u10i*a0i + u11r*a1r - u11i*a1i;
                    ai[r2] = u10r*a0i + u10i*a0r + u11r*a1i + u11i*a1r;
                }
            }
        }
    }

    // ---- readout: z_i = sum p * (-1)^popcount(idx & prefix_mask_i) ---------
    float p[16];
    #pragma unroll
    for (int r = 0; r < 16; r++) p[r] = ar[r]*ar[r] + ai[r]*ai[r];
    float us[8], ds[8];
    #pragma unroll
    for (int k = 0; k < 8; k++) { us[k] = p[2*k] + p[2*k+1]; ds[k] = p[2*k] - p[2*k+1]; }
    float S  = ((us[0]+us[1]) + (us[2]+us[3])) + ((us[4]+us[5]) + (us[6]+us[7]));
    float T0 = ((ds[0]+ds[1]) + (ds[2]+ds[3])) + ((ds[4]+ds[5]) + (ds[6]+ds[7]));
    float e0 = ds[0]-ds[1], e1 = ds[2]-ds[3], e2 = ds[4]-ds[5], e3 = ds[6]-ds[7];
    float T1 = (e0+e1) + (e2+e3);
    float f0 = e0-e1, f1 = e2-e3;
    float T2 = f0 + f1;
    float T3 = f0 - f1;

    float z[10];
    #pragma unroll
    for (int i = 0; i < 6; i++) {
        float v = S;
        #pragma unroll
        for (int b = 0; b < 6; b++) {
            float t = __shfl_xor(v, 1 << b, 64);
            if (b <= i) v = ((lane >> b) & 1) ? (t - v) : (v - t);
            else        v = v + t;
        }
        z[i] = v;
    }
    {
        float tv[4] = {T0, T1, T2, T3};
        #pragma unroll
        for (int j2 = 0; j2 < 4; j2++) {
            float v = tv[j2];
            #pragma unroll
            for (int b = 0; b < 6; b++) {
                float t = __shfl_xor(v, 1 << b, 64);
                v = ((lane >> b) & 1) ? (t - v) : (v - t);
            }
            z[6+j2] = v;
        }
    }

    // ---- tail MLP: z -> relu(16) -> 2 (redundant per lane, lane0 stores) ---
    float acc0 = b4[0], acc1 = b4[1];
    #pragma unroll
    for (int j2 = 0; j2 < 16; j2++) {
        float a = b3[j2];
        #pragma unroll
        for (int q = 0; q < 10; q++) a = fmaf(W3[j2*10 + q], z[q], a);
        a = fmaxf(a, 0.0f);
        acc0 = fmaf(W4[j2],      a, acc0);
        acc1 = fmaf(W4[16 + j2], a, acc1);
    }
    if (lane == 0) {
        reinterpret_cast<float2*>(out)[s] = make_float2(acc0, acc1);
    }
}

extern "C" void kernel_launch(void* const* d_in, const int* in_sizes, int n_in,
                              void* d_out, int out_size, void* d_ws, size_t ws_size,
                              hipStream_t stream)
{
    (void)in_sizes; (void)n_in; (void)out_size; (void)ws_size;
    const float* x  = (const float*)d_in[0];
    const float* W1 = (const float*)d_in[1];
    const float* b1 = (const float*)d_in[2];
    const float* W2 = (const float*)d_in[3];
    const float* b2 = (const float*)d_in[4];
    const float* qp = (const float*)d_in[5];
    const float* W3 = (const float*)d_in[6];
    const float* b3 = (const float*)d_in[7];
    const float* W4 = (const float*)d_in[8];
    const float* b4 = (const float*)d_in[9];
    float* ws  = (float*)d_ws;
    float* out = (float*)d_out;

    k_prep<<<1, 64, 0, stream>>>(qp, ws);
    k_qsim<<<4096, 256, 0, stream>>>(x, W1, b1, W2, b2, ws, W3, b3, W4, b4, out);
}

// Round 3
// 304.516 us; speedup vs baseline: 1.4811x; 1.4811x over previous
//
#include <hip/hip_runtime.h>

// ---------------------------------------------------------------------------
// helpers: cross-lane primitives (VALU where possible, DS only for xor4/16)
// ---------------------------------------------------------------------------
__device__ __forceinline__ int   f2i(float x){ return __builtin_bit_cast(int, x); }
__device__ __forceinline__ float i2f(int x)  { return __builtin_bit_cast(float, x); }

template<int CTRL>
__device__ __forceinline__ float dppf(float x){
    return i2f(__builtin_amdgcn_mov_dpp(f2i(x), CTRL, 0xF, 0xF, true));
}
template<int PAT>
__device__ __forceinline__ float swzf(float x){
    return i2f(__builtin_amdgcn_ds_swizzle(f2i(x), PAT));
}
// xor32 via permlane32_swap, convention-immune: self-swap returns the two
// 32-half duplicates in some order; partner = r0 + r1 - own.
__device__ __forceinline__ float xor32f(float x){
    unsigned ux = __builtin_bit_cast(unsigned, x);
    auto r = __builtin_amdgcn_permlane32_swap(ux, ux, false, false);
    float a = __builtin_bit_cast(float, (unsigned)r[0]);
    float b = __builtin_bit_cast(float, (unsigned)r[1]);
    return (a + b) - x;
}
// lane-xor on bit B
template<int B>
__device__ __forceinline__ float lx(float x){
    if constexpr      (B == 0) return dppf<0xB1>(x);    // quad_perm [1,0,3,2]
    else if constexpr (B == 1) return dppf<0x4E>(x);    // quad_perm [2,3,0,1]
    else if constexpr (B == 2) return swzf<0x101F>(x);  // ds_swizzle xor4
    else if constexpr (B == 3) return dppf<0x128>(x);   // row_ror:8 == xor8
    else if constexpr (B == 4) return swzf<0x401F>(x);  // ds_swizzle xor16
    else                       return xor32f(x);        // permlane32_swap
}

// ---------------------------------------------------------------------------
// prep: build 60 fused gate matrices U = RZ*RY*RX from q_params (f32)
// ---------------------------------------------------------------------------
__global__ void k_prep(const float* __restrict__ qp, float* __restrict__ ws)
{
    int t = threadIdx.x;
    if (t >= 60) return;
    int l = t / 10;
    float tx = 0.5f * qp[t*3 + 0];
    float ty = 0.5f * qp[t*3 + 1];
    float tz = 0.5f * qp[t*3 + 2];
    float cx = cosf(tx), sx = sinf(tx);
    float cy = cosf(ty), sy = sinf(ty);
    float cz, sz;
    if (l == 5) { cz = 1.0f; sz = 0.0f; }   // final RZ commutes with Z readout
    else        { cz = cosf(tz); sz = sinf(tz); }
    float m00r =  cy*cx, m00i =  sy*sx;
    float m01r = -sy*cx, m01i = -cy*sx;
    float m10r =  sy*cx, m10i = -cy*sx;
    float m11r =  cy*cx, m11i = -sy*sx;
    float* U = ws + t*8;
    U[0] = m00r*cz + m00i*sz;  U[1] = m00i*cz - m00r*sz;
    U[2] = m01r*cz + m01i*sz;  U[3] = m01i*cz - m01r*sz;
    U[4] = m10r*cz - m10i*sz;  U[5] = m10i*cz + m10r*sz;
    U[6] = m11r*cz - m11i*sz;  U[7] = m11i*cz + m11r*sz;
}

// ---------------------------------------------------------------------------
// quantum sim: 1 wave = 1 sample; qubit q<6 -> lane bit q, q>=6 -> reg bit q-6
// ---------------------------------------------------------------------------
template<int Q>
__device__ __forceinline__ void lane_gate(float (&ar)[16], float (&ai)[16],
                                          const float* __restrict__ U, int lane)
{
    float u00r=U[0], u00i=U[1], u01r=U[2], u01i=U[3];
    float u10r=U[4], u10i=U[5], u11r=U[6], u11i=U[7];
    bool hi = (lane >> Q) & 1;
    float msr = hi ? u11r : u00r, msi = hi ? u11i : u00i;
    float mor = hi ? u10r : u01r, moi = hi ? u10i : u01i;
    #pragma unroll
    for (int r = 0; r < 16; r++){
        float o_r = lx<Q>(ar[r]);
        float o_i = lx<Q>(ai[r]);
        float nr = msr*ar[r] - msi*ai[r] + mor*o_r - moi*o_i;
        float ni = msr*ai[r] + msi*ar[r] + mor*o_i + moi*o_r;
        ar[r] = nr; ai[r] = ni;
    }
}

template<int B>
__device__ __forceinline__ float bf_signed(float v, int lane){
    float t = lx<B>(v);
    return ((lane >> B) & 1) ? (t - v) : (v - t);
}
template<int B>
__device__ __forceinline__ float bf_plain(float v){ return v + lx<B>(v); }

template<int I>
__device__ __forceinline__ float z_mixed(float S, int lane){
    float v = bf_signed<0>(S, lane);
    if constexpr (I >= 1) v = bf_signed<1>(v, lane); else v = bf_plain<1>(v);
    if constexpr (I >= 2) v = bf_signed<2>(v, lane); else v = bf_plain<2>(v);
    if constexpr (I >= 3) v = bf_signed<3>(v, lane); else v = bf_plain<3>(v);
    if constexpr (I >= 4) v = bf_signed<4>(v, lane); else v = bf_plain<4>(v);
    if constexpr (I >= 5) v = bf_signed<5>(v, lane); else v = bf_plain<5>(v);
    return v;
}

__global__ __launch_bounds__(256) void k_qsim(
        const float* __restrict__ x,
        const float* __restrict__ W1, const float* __restrict__ b1,
        const float* __restrict__ W2, const float* __restrict__ b2,
        const float* __restrict__ ws,
        const float* __restrict__ W3, const float* __restrict__ b3,
        const float* __restrict__ W4, const float* __restrict__ b4,
        float* __restrict__ out)
{
    const int lane = threadIdx.x & 63;
    int wid = (blockIdx.x * 256 + threadIdx.x) >> 6;
    const int s = __builtin_amdgcn_readfirstlane(wid);

    // ---- fused front MLP: x(64) -> relu h(32) -> 10 angles -> cos/sin ------
    float cv[10], sv[10];
    {
        const float* xr  = x + s * 64;            // wave-uniform -> s_loads
        const int j = lane & 31;                  // lanes j and j+32 do row j
        const float* w1r = W1 + j * 64;
        float a = b1[j];
        #pragma unroll
        for (int k = 0; k < 64; k++) a = fmaf(w1r[k], xr[k], a);
        float h = fmaxf(a, 0.0f);

        float tsel = 0.0f;
        #pragma unroll
        for (int i = 0; i < 10; i++) {
            float t = W2[i*32 + j] * h;
            t = bf_plain<4>(t);  t = bf_plain<3>(t);  t = bf_plain<2>(t);
            t = bf_plain<1>(t);  t = bf_plain<0>(t);  // sum over 32-lane group
            t += b2[i];
            if (lane == i) tsel = t;               // lane i keeps angle i
        }
        float ang = tanhf(tsel) * 1.5707963267948966f;   // (tanh*pi)*0.5
        float sA, cA;
        __sincosf(ang, &sA, &cA);
        #pragma unroll
        for (int q = 0; q < 10; q++) {
            cv[q] = i2f(__builtin_amdgcn_readlane(f2i(cA), q));
            sv[q] = i2f(__builtin_amdgcn_readlane(f2i(sA), q));
        }
    }

    float ar[16], ai[16];

    // ---- init: RY-encoding product state with layer-0 1q gates folded in ---
    {
        const float* U0 = ws;
        float Lr, Li;
        {
            float v0r = U0[0]*cv[0] + U0[2]*sv[0], v0i = U0[1]*cv[0] + U0[3]*sv[0];
            float v1r = U0[4]*cv[0] + U0[6]*sv[0], v1i = U0[5]*cv[0] + U0[7]*sv[0];
            bool b = lane & 1;
            Lr = b ? v1r : v0r;  Li = b ? v1i : v0i;
        }
        #pragma unroll
        for (int q = 1; q < 6; q++) {
            const float* U = U0 + q*8;
            float v0r = U[0]*cv[q] + U[2]*sv[q], v0i = U[1]*cv[q] + U[3]*sv[q];
            float v1r = U[4]*cv[q] + U[6]*sv[q], v1i = U[5]*cv[q] + U[7]*sv[q];
            bool b = (lane >> q) & 1;
            float fr = b ? v1r : v0r, fi = b ? v1i : v0i;
            float nr = Lr*fr - Li*fi;
            float ni = Lr*fi + Li*fr;
            Lr = nr; Li = ni;
        }
        float vr[4][2], vi[4][2];
        #pragma unroll
        for (int q = 6; q < 10; q++) {
            const float* U = U0 + q*8;
            vr[q-6][0] = U[0]*cv[q] + U[2]*sv[q];  vi[q-6][0] = U[1]*cv[q] + U[3]*sv[q];
            vr[q-6][1] = U[4]*cv[q] + U[6]*sv[q];  vi[q-6][1] = U[5]*cv[q] + U[7]*sv[q];
        }
        float t67r[4], t67i[4], t89r[4], t89i[4];
        #pragma unroll
        for (int m = 0; m < 4; m++) {
            int b0 = m & 1, b1i = (m >> 1) & 1;
            t67r[m] = vr[0][b0]*vr[1][b1i] - vi[0][b0]*vi[1][b1i];
            t67i[m] = vr[0][b0]*vi[1][b1i] + vi[0][b0]*vr[1][b1i];
            t89r[m] = vr[2][b0]*vr[3][b1i] - vi[2][b0]*vi[3][b1i];
            t89i[m] = vr[2][b0]*vi[3][b1i] + vi[2][b0]*vr[3][b1i];
        }
        #pragma unroll
        for (int r = 0; r < 16; r++) {
            int lo = r & 3, hi = r >> 2;
            float pr  = t67r[lo]*t89r[hi] - t67i[lo]*t89i[hi];
            float pi_ = t67r[lo]*t89i[hi] + t67i[lo]*t89r[hi];
            ar[r] = Lr*pr - Li*pi_;
            ai[r] = Lr*pi_ + Li*pr;
        }
    }

    // ---- composed CNOT chain setup ----------------------------------------
    // chain CNOT(0,1)..CNOT(8,9) == index map: bit k -> parity(b0..bk).
    // Gather: src lane = (lane ^ lane<<1)&63 ; src reg = f(R') ^ parity6(lane)
    // with f = prefix-parity-inverse on 4 bits (compile-time cycles).
    const int  baddr = ((lane ^ (lane << 1)) & 63) << 2;
    const bool lpar  = __builtin_popcount(lane & 63) & 1;
    #define BP(xx) i2f(__builtin_amdgcn_ds_bpermute(baddr, f2i(xx)))
    #define CHAIN_COMPOSED() {                                                 \
        _Pragma("unroll")                                                      \
        for (int k = 0; k < 8; k++) {          /* cond. pair swap (lpar) */    \
            float e0 = ar[2*k], o0 = ar[2*k+1];                                \
            ar[2*k]   = lpar ? o0 : e0;                                        \
            ar[2*k+1] = lpar ? e0 : o0;                                        \
            float e1 = ai[2*k], o1 = ai[2*k+1];                                \
            ai[2*k]   = lpar ? o1 : e1;                                        \
            ai[2*k+1] = lpar ? e1 : o1;                                        \
        }                                                                      \
        /* dest R' <- bpermute(src reg f(R')); cycles of f:                */  \
        /* {0},{8},(1,3,5,15),(2,6,10,14),(4,12),(7,9,11,13)               */  \
        ar[0] = BP(ar[0]);  ai[0] = BP(ai[0]);                                 \
        ar[8] = BP(ar[8]);  ai[8] = BP(ai[8]);                                 \
        { float t=ar[1]; ar[1]=BP(ar[3]);  ar[3]=BP(ar[5]);                    \
          ar[5]=BP(ar[15]); ar[15]=BP(t); }                                    \
        { float t=ai[1]; ai[1]=BP(ai[3]);  ai[3]=BP(ai[5]);                    \
          ai[5]=BP(ai[15]); ai[15]=BP(t); }                                    \
        { float t=ar[2]; ar[2]=BP(ar[6]);  ar[6]=BP(ar[10]);                   \
          ar[10]=BP(ar[14]); ar[14]=BP(t); }                                   \
        { float t=ai[2]; ai[2]=BP(ai[6]);  ai[6]=BP(ai[10]);                   \
          ai[10]=BP(ai[14]); ai[14]=BP(t); }                                   \
        { float t=ar[4]; ar[4]=BP(ar[12]); ar[12]=BP(t); }                     \
        { float t=ai[4]; ai[4]=BP(ai[12]); ai[12]=BP(t); }                     \
        { float t=ar[7]; ar[7]=BP(ar[9]);  ar[9]=BP(ar[11]);                   \
          ar[11]=BP(ar[13]); ar[13]=BP(t); }                                   \
        { float t=ai[7]; ai[7]=BP(ai[9]);  ai[9]=BP(ai[11]);                   \
          ai[11]=BP(ai[13]); ai[13]=BP(t); }                                   \
    }

    // ---- layers: chain(l-1) then gates(l), l = 1..5 (last chain folded) ----
    #pragma unroll 1
    for (int l = 1; l < 6; ++l) {
        CHAIN_COMPOSED();
        const float* Ub = ws + l * 80;
        lane_gate<0>(ar, ai, Ub +  0, lane);
        lane_gate<1>(ar, ai, Ub +  8, lane);
        lane_gate<2>(ar, ai, Ub + 16, lane);
        lane_gate<3>(ar, ai, Ub + 24, lane);
        lane_gate<4>(ar, ai, Ub + 32, lane);
        lane_gate<5>(ar, ai, Ub + 40, lane);
        // register-bit qubits 6..9
        #pragma unroll
        for (int qq = 0; qq < 4; qq++) {
            const float* U = Ub + (6+qq)*8;
            float u00r=U[0], u00i=U[1], u01r=U[2], u01i=U[3];
            float u10r=U[4], u10i=U[5], u11r=U[6], u11i=U[7];
            const int m = 1 << qq;
            #pragma unroll
            for (int r = 0; r < 16; r++) {
                if (!(r & m)) {
                    const int r2 = r | m;
                    float a0r=ar[r], a0i=ai[r], a1r=ar[r2], a1i=ai[r2];
                    ar[r]  = u00r*a0r - u00i*a0i + u01r*a1r - u01i*a1i;
                    ai[r]  = u00r*a0i + u00i*a0r + u01r*a1i + u01i*a1r;
                    ar[r2] = u10r*a0r - u10i*a0i + u11r*a1r - u11i*a1i;
                    ai[r2] = u10r*a0i + u10i*a0r + u11r*a1i + u11i*a1r;
                }
            }
        }
    }

    // ---- readout: z_i = sum p * (-1)^popcount(idx & prefix_mask_i) ---------
    float p[16];
    #pragma unroll
    for (int r = 0; r < 16; r++) p[r] = ar[r]*ar[r] + ai[r]*ai[r];
    float us[8], ds[8];
    #pragma unroll
    for (int k = 0; k < 8; k++) { us[k] = p[2*k] + p[2*k+1]; ds[k] = p[2*k] - p[2*k+1]; }
    float S  = ((us[0]+us[1]) + (us[2]+us[3])) + ((us[4]+us[5]) + (us[6]+us[7]));
    float T0 = ((ds[0]+ds[1]) + (ds[2]+ds[3])) + ((ds[4]+ds[5]) + (ds[6]+ds[7]));
    float e0 = ds[0]-ds[1], e1 = ds[2]-ds[3], e2 = ds[4]-ds[5], e3 = ds[6]-ds[7];
    float T1 = (e0+e1) + (e2+e3);
    float f0 = e0-e1, f1 = e2-e3;
    float T2 = f0 + f1;
    float T3 = f0 - f1;

    float z[10];
    z[0] = z_mixed<0>(S, lane);
    z[1] = z_mixed<1>(S, lane);
    z[2] = z_mixed<2>(S, lane);
    z[3] = z_mixed<3>(S, lane);
    z[4] = z_mixed<4>(S, lane);
    z[5] = z_mixed<5>(S, lane);
    z[6] = z_mixed<5>(T0, lane);
    z[7] = z_mixed<5>(T1, lane);
    z[8] = z_mixed<5>(T2, lane);
    z[9] = z_mixed<5>(T3, lane);

    // ---- tail MLP: z -> relu(16) -> 2 (redundant per lane, lane0 stores) ---
    float acc0 = b4[0], acc1 = b4[1];
    #pragma unroll
    for (int j2 = 0; j2 < 16; j2++) {
        float a = b3[j2];
        #pragma unroll
        for (int q = 0; q < 10; q++) a = fmaf(W3[j2*10 + q], z[q], a);
        a = fmaxf(a, 0.0f);
        acc0 = fmaf(W4[j2],      a, acc0);
        acc1 = fmaf(W4[16 + j2], a, acc1);
    }
    if (lane == 0) {
        reinterpret_cast<float2*>(out)[s] = make_float2(acc0, acc1);
    }
}

extern "C" void kernel_launch(void* const* d_in, const int* in_sizes, int n_in,
                              void* d_out, int out_size, void* d_ws, size_t ws_size,
                              hipStream_t stream)
{
    (void)in_sizes; (void)n_in; (void)out_size; (void)ws_size;
    const float* x  = (const float*)d_in[0];
    const float* W1 = (const float*)d_in[1];
    const float* b1 = (const float*)d_in[2];
    const float* W2 = (const float*)d_in[3];
    const float* b2 = (const float*)d_in[4];
    const float* qp = (const float*)d_in[5];
    const float* W3 = (const float*)d_in[6];
    const float* b3 = (const float*)d_in[7];
    const float* W4 = (const float*)d_in[8];
    const float* b4 = (const float*)d_in[9];
    float* ws  = (float*)d_ws;
    float* out = (float*)d_out;

    k_prep<<<1, 64, 0, stream>>>(qp, ws);
    k_qsim<<<4096, 256, 0, stream>>>(x, W1, b1, W2, b2, ws, W3, b3, W4, b4, out);
}